// Round 15
// baseline (120.976 us; speedup 1.0000x reference)
//
#include <hip/hip_runtime.h>
#include <cstdint>
#include <cstddef>

// NonLocalBlock3D: B=2, C=256, Ci=128, N=D*H*W=8192.
// k1 projections (512thr, half-split + W-prefetch dbuf) -> k2 flash attention (CH=4,
// 2-tiles/barrier, wave-parity-staggered tile order) -> k3 combine+wy GEMM+stats
// (512thr, W-prefetch) -> k4 BN+res.
// R3: never cap k2 VGPR via launch_bounds min-waves (spills). (512,2) safe.
// R4: k2 unified regs ~168/wave -> 2 waves/SIMD hard cap.
// R6: global_load_lds staging regressed. Keep reg-staged write-late.
// R7/R8: __builtin_amdgcn_exp2f; (row&15)<<4 swizzle over 256B rows.
// R9/R10/R11/R13 k2 micro-structure: all NEUTRAL. R12/R14 tail: WIN (~-11us).
// R15: wave-parity tile-order stagger — even waves (A,B), odd waves (B,A); both tiles
//      already co-resident in LDS, so half the waves run MFMA while half run VALU
//      (m114: cross-wave pipe overlap). Zero-cost phase decorrelation.

typedef unsigned short u16;
typedef __bf16 bf16x8 __attribute__((ext_vector_type(8)));
typedef float f32x4 __attribute__((ext_vector_type(4)));
typedef float f32x16 __attribute__((ext_vector_type(16)));
typedef unsigned short u16x8 __attribute__((ext_vector_type(8)));

#define B_ 2
#define C_ 256
#define CI_ 128
#define N_ 8192
#define KVB 64

static __device__ __forceinline__ u16 f2bf(float f){
  unsigned u = __builtin_bit_cast(unsigned, f);
  unsigned r = (u + 0x7FFFu + ((u>>16)&1u)) >> 16;
  return (u16)r;
}
static __device__ __forceinline__ float bf2f(u16 v){
  unsigned u = ((unsigned)v) << 16;
  return __builtin_bit_cast(float, u);
}
static __device__ __forceinline__ float fexp2(float x){
  return __builtin_amdgcn_exp2f(x);     // raw v_exp_f32
}
static __device__ __forceinline__ f32x4 f4zero(){
  f32x4 v; v[0]=0.f; v[1]=0.f; v[2]=0.f; v[3]=0.f; return v;
}
static __device__ __forceinline__ f32x16 f16zero(){
  f32x16 v;
#pragma unroll
  for (int i=0;i<16;i++) v[i]=0.f;
  return v;
}
static __device__ __forceinline__ f32x4 mfma16(bf16x8 a, bf16x8 b, f32x4 c){
  return __builtin_amdgcn_mfma_f32_16x16x32_bf16(a, b, c, 0, 0, 0);
}
static __device__ __forceinline__ f32x16 mfma32(bf16x8 a, bf16x8 b, f32x16 c){
  return __builtin_amdgcn_mfma_f32_32x32x16_bf16(a, b, c, 0, 0, 0);
}
static __device__ __forceinline__ unsigned cvtpk(float lo, float hi){
  unsigned r;
  asm("v_cvt_pk_bf16_f32 %0, %1, %2" : "=v"(r) : "v"(lo), "v"(hi));
  return r;
}
static __device__ __forceinline__ void plswap(unsigned &a, unsigned &b){
  asm volatile("v_permlane32_swap_b32 %0, %1" : "+v"(a), "+v"(b));
}

#define LOG2E 1.4426950408889634f

// ---------------- K1: fused weight pack + transpose + 3 projections ----------------
__global__ __launch_bounds__(512) void k1_proj(const float* __restrict__ x,
     const float* __restrict__ Wt, const float* __restrict__ Wp,
     const float* __restrict__ Wg, const float* __restrict__ bt,
     const float* __restrict__ bp, const float* __restrict__ bg,
     u16* __restrict__ theta, u16* __restrict__ kproj, u16* __restrict__ gT,
     float* __restrict__ stats){
  __shared__ u16 At[64*264];            // 33792 B
  __shared__ u16 Wt2[2][2][32*264];     // [half][buf], 4 x 16896 B
  int tid = threadIdx.x;
  int b  = blockIdx.x >> 7;
  int nb = (blockIdx.x & 127) * 64;
  int w = tid >> 6, lane = tid & 63;
  int l15 = lane & 15, kg = lane >> 4;
  int half = w >> 2, wq = w & 3;
  int ht = tid & 255;
  int o8 = ht>>3, cp8 = ht&7;

  if (blockIdx.x == 0){ stats[tid] = 0.f; }

  auto wrow = [&](int och)->const float* {
    return (och<4) ? (Wt + ((size_t)(och*32 + o8))*256)
         : (och<8) ? (Wp + ((size_t)((och-4)*32 + o8))*256)
                   : (Wg + ((size_t)((och-8)*32 + o8))*256);
  };

  // stage A tile [64 n][256 c] bf16 (transposed from x)
  {
    int cp = tid & 127, nh = tid >> 7;
    int c0 = cp*2;
    const float* src0 = x + ((size_t)(b*C_ + c0))*N_ + nb + nh*16;
    const float* src1 = src0 + N_;
#pragma unroll
    for (int j=0;j<4;j++){
      f32x4 a = *(const f32x4*)(src0 + j*4);
      f32x4 c = *(const f32x4*)(src1 + j*4);
#pragma unroll
      for (int q=0;q<4;q++){
        unsigned pk = (unsigned)f2bf(a[q]) | ((unsigned)f2bf(c[q])<<16);
        *(unsigned*)&At[(nh*16 + j*4 + q)*264 + c0] = pk;
      }
    }
  }
  // stage W chunk (half*6) into buf 0
  {
    int och = half*6;
    const float* src = wrow(och) + cp8*8;
    float scl = (och<4) ? LOG2E : 1.f;
#pragma unroll
    for (int j=0;j<4;j++){
      f32x4 w0 = *(const f32x4*)(src + j*64);
      f32x4 w1 = *(const f32x4*)(src + j*64 + 4);
      u16 tmp[8];
#pragma unroll
      for (int q=0;q<4;q++){ tmp[q] = f2bf(w0[q]*scl); tmp[4+q] = f2bf(w1[q]*scl); }
      *(u16x8*)&Wt2[half][0][o8*264 + cp8*8 + j*64] = *(const u16x8*)tmp;
    }
  }
  __syncthreads();

  bf16x8 afr[8];
#pragma unroll
  for (int kc=0;kc<8;kc++)
    afr[kc] = *(const bf16x8*)&At[(wq*16+l15)*264 + kc*32 + kg*8];

  for (int i = 0; i < 6; i++){
    int och = half*6 + i;
    // prefetch next W chunk into registers (write-late)
    f32x4 pw[8];
    if (i < 5){
      const float* src = wrow(och+1) + cp8*8;
#pragma unroll
      for (int j=0;j<4;j++){
        pw[2*j]   = *(const f32x4*)(src + j*64);
        pw[2*j+1] = *(const f32x4*)(src + j*64 + 4);
      }
    }

    f32x4 acc0 = f4zero(), acc1 = f4zero();
    const u16* wb = &Wt2[half][i&1][0];
#pragma unroll
    for (int kc=0;kc<8;kc++){
      bf16x8 b0 = *(const bf16x8*)&wb[(l15)*264 + kc*32 + kg*8];
      bf16x8 b1 = *(const bf16x8*)&wb[(16+l15)*264 + kc*32 + kg*8];
      acc0 = mfma16(afr[kc], b0, acc0);
      acc1 = mfma16(afr[kc], b1, acc1);
    }

    // write-late: staged W regs -> other buffer
    if (i < 5){
      float scl = (och+1<4) ? LOG2E : 1.f;
#pragma unroll
      for (int j=0;j<4;j++){
        u16 tmp[8];
#pragma unroll
        for (int q=0;q<4;q++){ tmp[q] = f2bf(pw[2*j][q]*scl); tmp[4+q] = f2bf(pw[2*j+1][q]*scl); }
        *(u16x8*)&Wt2[half][(i+1)&1][o8*264 + cp8*8 + j*64] = *(const u16x8*)tmp;
      }
    }

    if (och < 8){
      u16* dst = (och < 4) ? theta : kproj;
      int oo = (och & 3) * 32;
#pragma unroll
      for (int of=0;of<2;of++){
        int o = oo + of*16 + l15;
        float bias = (och<4) ? bt[och*32 + of*16 + l15] * LOG2E
                             : bp[(och-4)*32 + of*16 + l15];
        f32x4 acc = of ? acc1 : acc0;
#pragma unroll
        for (int i2=0;i2<4;i2++){
          int n = nb + wq*16 + kg*4 + i2;
          dst[((size_t)b*N_ + n)*CI_ + o] = f2bf(acc[i2] + bias);
        }
      }
    } else {
#pragma unroll
      for (int of=0;of<2;of++){
        int o = of*16 + l15;
        int og = (och-8)*32 + o;
        float bias = bg[og];
        f32x4 acc = of ? acc1 : acc0;
        unsigned lo = (unsigned)f2bf(acc[0]+bias) | ((unsigned)f2bf(acc[1]+bias)<<16);
        unsigned hi2 = (unsigned)f2bf(acc[2]+bias) | ((unsigned)f2bf(acc[3]+bias)<<16);
        uint2 val; val.x = lo; val.y = hi2;
        *(uint2*)(gT + ((size_t)b*CI_ + og)*N_ + nb + wq*16 + kg*4) = val;
      }
    }
    __syncthreads();
  }
}

// ---------------- K2: flash attention, 2 tiles/barrier, parity-staggered order ----------
// Grid 256 x 512 (8 waves x 32 q). bid&7 = (b,chunk) -> XCD.
// LDS 128K: K halves [2][2 tiles][16K] at 0; V halves [2][128 c][256B] at 64K.
// Even waves process (tileA, tileB); odd waves (tileB, tileA) -> cross-wave MFMA/VALU overlap.
__global__ __launch_bounds__(512, 2) void k2_attn(const u16* __restrict__ theta,
      const u16* __restrict__ kproj, const u16* __restrict__ gT,
      u16* __restrict__ pO, float* __restrict__ pM, float* __restrict__ pL){
  constexpr int CHUNK_N = 2048;
  constexpr int NTI = CHUNK_N / KVB;   // 32
  constexpr int NS  = NTI/2;           // 16 super-iters
  __shared__ char smem[131072];
  char* kbase = smem;
  char* vbase = smem + 65536;
  int tid = threadIdx.x;
  int bid = blockIdx.x;
  int combo = bid & 7;
  int b = combo & 1;
  int chunk = combo >> 1;
  int qblk = bid >> 3;
  int n0 = chunk * CHUNK_N;
  int w = tid >> 6, lane = tid & 63;
  int l31 = lane & 31, hi = lane >> 5;
  int qg = qblk*256 + w*32 + l31;
  int wodd = w & 1;

  bf16x8 qf[8];
  {
    const u16* qsrc = theta + ((size_t)b*N_ + qg)*CI_ + hi*8;
#pragma unroll
    for (int cc=0; cc<8; cc++) qf[cc] = *(const bf16x8*)(qsrc + cc*16);
  }

  int krow_s = tid >> 3, kpart = tid & 7;
  int vrow_s = tid >> 2, vpart = tid & 3;
  const u16* ksrc = kproj + ((size_t)b*N_ + n0 + krow_s)*CI_ + kpart*16;
  const u16* vsrc = gT + ((size_t)b*CI_ + vrow_s)*N_ + n0 + vpart*32;
  int kw_off[2], vw_off[4];
#pragma unroll
  for (int j=0;j<2;j++){
    int cb = kpart*32 + j*16;
    kw_off[j] = krow_s*256 + (cb ^ ((krow_s&15)<<4));
  }
#pragma unroll
  for (int j=0;j<4;j++){
    vw_off[j] = vrow_s*256 + ((vpart*64 + j*16) ^ ((vrow_s&15)<<4));
  }
  int kswz = (l31&15)<<4;
  int kro[8];
#pragma unroll
  for (int cc=0;cc<8;cc++) kro[cc] = l31*256 + ((cc*32 + hi*16) ^ kswz);

  // prologue: stage pair 0 into half 0
#pragma unroll
  for (int j=0;j<2;j++){
    *(u16x8*)(kbase + kw_off[j])         = *(const u16x8*)(ksrc + j*8);
    *(u16x8*)(kbase + 16384 + kw_off[j]) = *(const u16x8*)(ksrc + (size_t)KVB*CI_ + j*8);
  }
#pragma unroll
  for (int j=0;j<4;j++)
    *(u16x8*)(vbase + vw_off[j]) = *(const u16x8*)(vsrc + j*8);
  __syncthreads();

  f32x16 oacc[4];
#pragma unroll
  for (int i=0;i<4;i++) oacc[i] = f16zero();
  float mrun = -1e30f, lrun = 0.f;

#define K2_TILE(KB, VB, VX) { \
    f32x16 sA = f16zero(), sB = f16zero(); \
    __builtin_amdgcn_s_setprio(1); \
    _Pragma("unroll") \
    for (int cc=0; cc<8; cc++){ \
      bf16x8 kf0 = *(const bf16x8*)((KB) + kro[cc]); \
      bf16x8 kf1 = *(const bf16x8*)((KB) + 8192 + kro[cc]); \
      sA = mfma32(kf0, qf[cc], sA); \
      sB = mfma32(kf1, qf[cc], sB); \
    } \
    __builtin_amdgcn_s_setprio(0); \
    float t8[8]; \
    _Pragma("unroll") \
    for (int i=0;i<8;i++) t8[i] = fmaxf(fmaxf(sA[i], sA[i+8]), fmaxf(sB[i], sB[i+8])); \
    float mx = fmaxf(fmaxf(fmaxf(t8[0],t8[4]),fmaxf(t8[1],t8[5])), \
                     fmaxf(fmaxf(t8[2],t8[6]),fmaxf(t8[3],t8[7]))); \
    mx = fmaxf(mx, __shfl_xor(mx, 32)); \
    if (__any(mx > mrun + 12.f)){ \
      float mnew = fmaxf(mrun, mx); \
      float sc = fexp2(mrun - mnew); \
      lrun *= sc; \
      _Pragma("unroll") \
      for (int i=0;i<4;i++){ _Pragma("unroll") for (int r=0;r<16;r++) oacc[i][r] *= sc; } \
      mrun = mnew; } \
    float pA[16], pB[16]; \
    _Pragma("unroll") \
    for (int r=0;r<16;r++){ pA[r] = fexp2(sA[r]-mrun); pB[r] = fexp2(sB[r]-mrun); } \
    { float s8[8]; \
      _Pragma("unroll") \
      for (int i=0;i<8;i++) s8[i] = (pA[i]+pA[i+8]) + (pB[i]+pB[i+8]); \
      float ps = ((s8[0]+s8[4])+(s8[1]+s8[5])) + ((s8[2]+s8[6])+(s8[3]+s8[7])); \
      ps += __shfl_xor(ps, 32); lrun += ps; } \
    __builtin_amdgcn_s_setprio(1); \
    _Pragma("unroll") \
    for (int ks=0; ks<4; ks++){ \
      const float* P = (ks<2) ? pA : pB; \
      int r0 = (ks&1)*8; \
      unsigned a0 = cvtpk(P[r0+0], P[r0+1]); \
      unsigned b0 = cvtpk(P[r0+4], P[r0+5]); \
      unsigned a1 = cvtpk(P[r0+2], P[r0+3]); \
      unsigned b1 = cvtpk(P[r0+6], P[r0+7]); \
      plswap(a0, b0); plswap(a1, b1); \
      union { unsigned u[4]; bf16x8 v; } pb; \
      pb.u[0]=a0; pb.u[1]=a1; pb.u[2]=b0; pb.u[3]=b1; \
      _Pragma("unroll") \
      for (int c2=0; c2<4; c2++){ \
        bf16x8 vf = *(const bf16x8*)((VB) + c2*8192 + (kro[ks] ^ (VX))); \
        oacc[c2] = mfma32(vf, pb.v, oacc[c2]); \
      } \
    } \
    __builtin_amdgcn_s_setprio(0); }

  for (int s = 0; s < NS; s++){
    int H = s & 1;
    char* kh = kbase + H*32768;
    char* vh = vbase + H*32768;
    // parity stagger: even waves (A,B); odd waves (B,A)
    char* kt0 = kh + wodd*16384;
    char* kt1 = kh + (wodd^1)*16384;
    int vx0 = wodd ? 128 : 0;
    int vx1 = vx0 ^ 128;
    u16x8 kst[4], vst[4];
    bool pf = (s+1 < NS);
    if (pf){
      const u16* ks = ksrc + (size_t)(2*s+2)*KVB*CI_;
      const u16* vs = vsrc + (size_t)(s+1)*128;
      kst[0] = *(const u16x8*)(ks);
      kst[1] = *(const u16x8*)(ks + 8);
      kst[2] = *(const u16x8*)(ks + (size_t)KVB*CI_);
      kst[3] = *(const u16x8*)(ks + (size_t)KVB*CI_ + 8);
#pragma unroll
      for (int j=0;j<4;j++) vst[j] = *(const u16x8*)(vs + j*8);
    }

    // first tile (parity-dependent)
    K2_TILE(kt0, vh, vx0)

    // write-late: staged regs -> other half (hides load latency under first tile)
    if (pf){
      char* kd = kbase + (H^1)*32768;
      char* vd = vbase + (H^1)*32768;
#pragma unroll
      for (int j=0;j<2;j++){
        *(u16x8*)(kd + kw_off[j])         = kst[j];
        *(u16x8*)(kd + 16384 + kw_off[j]) = kst[2+j];
      }
#pragma unroll
      for (int j=0;j<4;j++)
        *(u16x8*)(vd + vw_off[j]) = vst[j];
    }

    // second tile
    K2_TILE(kt1, vh, vx1)

    __syncthreads();
  }

  // epilogue: O^T -> per-wave LDS region (bf16, swizzled) -> coalesced partial store
  char* region = smem + w*8192;
  int eswz = (l31&7)<<4;
#pragma unroll
  for (int c2=0;c2<4;c2++)
#pragma unroll
    for (int r=0;r<16;r++){
      int c = c2*32 + (r&3) + 8*(r>>2) + 4*hi;
      *(u16*)(region + l31*256 + ((c*2) ^ eswz)) = f2bf(oacc[c2][r]);
    }
  __syncthreads();
  {
    int ql = lane >> 1, half = lane & 1;
    int qg2 = qblk*256 + w*32 + ql;
    u16* dst = pO + ((size_t)(chunk*2 + b)*N_ + qg2)*CI_ + half*64;
    int rswz = (ql&7)<<4;
#pragma unroll
    for (int j=0;j<8;j++){
      u16x8 v2 = *(const u16x8*)(region + ql*256 + ((half*128 + j*16) ^ rswz));
      *(u16x8*)(dst + j*8) = v2;
    }
  }
  if (hi == 0){
    pM[(size_t)(chunk*2 + b)*N_ + qg] = mrun;
    pL[(size_t)(chunk*2 + b)*N_ + qg] = lrun;
  }
}

// ---------------- K3: fused combine(pO chunks) + wy = Ww @ y + bw + stats ----------------
__global__ __launch_bounds__(512) void k3_wy(const u16* __restrict__ pO,
    const float* __restrict__ pM, const float* __restrict__ pL,
    const float* __restrict__ Ww, const float* __restrict__ bw,
    u16* __restrict__ wy, float* __restrict__ stats){
  __shared__ u16 Yt[64*136];            // 17408
  __shared__ u16 Wt2[2][2][64*136];     // 4 x 17408
  __shared__ float wyb2[2][64*72];      // 2 x 18432
  int tid = threadIdx.x;
  int b  = blockIdx.x >> 7;
  int nb = (blockIdx.x & 127) * 64;
  int w = tid>>6, lane = tid&63;
  int l15 = lane&15, kg = lane>>4;
  int half = w >> 2, wq = w & 3;
  int ht = tid & 255;
  int o4 = ht>>2, cp4 = ht&3;

  // stage y tile [64 n][128 c]: combine 4 KV-chunk partials -> bf16
  {
    int n = tid>>3, cp = tid&7;
    size_t q = (size_t)nb + n;
    float m[4], l[4];
#pragma unroll
    for (int ch=0; ch<4; ch++){
      m[ch] = pM[(size_t)(ch*2+b)*N_ + q];
      l[ch] = pL[(size_t)(ch*2+b)*N_ + q];
    }
    float M = fmaxf(fmaxf(m[0],m[1]), fmaxf(m[2],m[3]));
    float wts[4]; float L = 0.f;
#pragma unroll
    for (int ch=0; ch<4; ch++){ wts[ch] = fexp2(m[ch]-M); L += wts[ch]*l[ch]; }
    float inv = 1.f/L;
#pragma unroll
    for (int j=0;j<2;j++){
      int c0 = cp*16 + j*8;
      float acc[8];
#pragma unroll
      for (int i=0;i<8;i++) acc[i]=0.f;
#pragma unroll
      for (int ch=0; ch<4; ch++){
        u16x8 v = *(const u16x8*)(pO + ((size_t)(ch*2+b)*N_ + q)*CI_ + c0);
#pragma unroll
        for (int i=0;i<8;i++) acc[i] += wts[ch]*bf2f(v[i]);
      }
#pragma unroll
      for (int i=0;i<4;i++){
        unsigned pk = (unsigned)f2bf(acc[2*i]*inv) | ((unsigned)f2bf(acc[2*i+1]*inv)<<16);
        *(unsigned*)&Yt[n*136 + c0 + 2*i] = pk;
      }
    }
  }
  // stage W chunk (half*2) into buf 0
  {
    const float* src = Ww + ((size_t)(half*2*64 + o4))*CI_ + cp4*32;
#pragma unroll
    for (int j=0;j<4;j++){
      f32x4 w0 = *(const f32x4*)(src + j*8);
      f32x4 w1 = *(const f32x4*)(src + j*8 + 4);
      u16 tmp[8];
#pragma unroll
      for (int q2=0;q2<4;q2++){ tmp[q2] = f2bf(w0[q2]); tmp[4+q2] = f2bf(w1[q2]); }
      *(u16x8*)&Wt2[half][0][o4*136 + cp4*32 + j*8] = *(const u16x8*)tmp;
    }
  }
  __syncthreads();

  bf16x8 afr[4];
#pragma unroll
  for (int kc=0;kc<4;kc++)
    afr[kc] = *(const bf16x8*)&Yt[(wq*16+l15)*136 + kc*32 + kg*8];

  for (int i = 0; i < 2; i++){
    int oc = half*2 + i;
    // prefetch next W chunk into regs
    f32x4 pw[8];
    if (i == 0){
      const float* src = Ww + ((size_t)((oc+1)*64 + o4))*CI_ + cp4*32;
#pragma unroll
      for (int j=0;j<4;j++){
        pw[2*j]   = *(const f32x4*)(src + j*8);
        pw[2*j+1] = *(const f32x4*)(src + j*8 + 4);
      }
    }

    f32x4 acc[4];
#pragma unroll
    for (int of=0;of<4;of++) acc[of] = f4zero();
    const u16* wb = &Wt2[half][i][0];
#pragma unroll
    for (int kc=0;kc<4;kc++){
#pragma unroll
      for (int of=0;of<4;of++){
        bf16x8 bfr = *(const bf16x8*)&wb[(of*16+l15)*136 + kc*32 + kg*8];
        acc[of] = mfma16(afr[kc], bfr, acc[of]);
      }
    }
#pragma unroll
    for (int of=0;of<4;of++){
#pragma unroll
      for (int i2=0;i2<4;i2++)
        wyb2[half][(of*16+l15)*72 + wq*16 + kg*4 + i2] = acc[of][i2];
    }
    // write-late: staged W regs -> buf 1
    if (i == 0){
#pragma unroll
      for (int j=0;j<4;j++){
        u16 tmp[8];
#pragma unroll
        for (int q2=0;q2<4;q2++){ tmp[q2] = f2bf(pw[2*j][q2]); tmp[4+q2] = f2bf(pw[2*j+1][q2]); }
        *(u16x8*)&Wt2[half][1][o4*136 + cp4*32 + j*8] = *(const u16x8*)tmp;
      }
    }
    __syncthreads();
    {
      int og = oc*64 + o4;
      float bias = bw[og];
      float sm = 0.f, sq = 0.f;
      u16* dst = wy + ((size_t)b*C_ + og)*N_ + nb + cp4*16;
      u16 buf[16];
#pragma unroll
      for (int j=0;j<4;j++){
#pragma unroll
        for (int q2=0;q2<4;q2++){
          float t2 = wyb2[half][o4*72 + cp4*16 + j*4 + q2] + bias;
          buf[j*4+q2] = f2bf(t2); sm += t2; sq += t2*t2;
        }
      }
      *(u16x8*)dst = *(const u16x8*)&buf[0];
      *(u16x8*)(dst+8) = *(const u16x8*)&buf[8];
      sm += __shfl_xor(sm, 1); sm += __shfl_xor(sm, 2);
      sq += __shfl_xor(sq, 1); sq += __shfl_xor(sq, 2);
      if ((tid&3)==0){
        atomicAdd(&stats[og], sm);
        atomicAdd(&stats[256+og], sq);
      }
    }
    __syncthreads();
  }
}

// ---------------- K4: BN (batch stats) + residual ----------------
__global__ __launch_bounds__(256) void k4_bn(const u16* __restrict__ wy,
    const float* __restrict__ x, const float* __restrict__ stats,
    const float* __restrict__ gamma, const float* __restrict__ beta,
    float* __restrict__ out){
  size_t base = ((size_t)blockIdx.x)*2048 + (size_t)threadIdx.x*8;
  int o = (int)((base >> 13) & 255);
  const float invn = 1.f/16384.f;
  float mean = stats[o]*invn;
  float var  = stats[256+o]*invn - mean*mean;
  float rs = rsqrtf(var + 1e-5f);
  float g = gamma[o]*rs;
  float bb = beta[o];
  u16x8 a = *(const u16x8*)(wy + base);
  f32x4 x0 = *(const f32x4*)(x + base);
  f32x4 x1 = *(const f32x4*)(x + base + 4);
  f32x4 r0, r1;
#pragma unroll
  for (int q=0;q<4;q++){
    r0[q] = (bf2f(a[q])-mean)*g + bb + x0[q];
    r1[q] = (bf2f(a[4+q])-mean)*g + bb + x1[q];
  }
  *(f32x4*)(out + base)     = r0;
  *(f32x4*)(out + base + 4) = r1;
}

extern "C" void kernel_launch(void* const* d_in, const int* in_sizes, int n_in,
                              void* d_out, int out_size, void* d_ws, size_t ws_size,
                              hipStream_t stream){
  const float* x     = (const float*)d_in[0];
  const float* Wt    = (const float*)d_in[1];
  const float* bt    = (const float*)d_in[2];
  const float* Wp    = (const float*)d_in[3];
  const float* bp    = (const float*)d_in[4];
  const float* Wg    = (const float*)d_in[5];
  const float* bg    = (const float*)d_in[6];
  const float* Ww    = (const float*)d_in[7];
  const float* bw    = (const float*)d_in[8];
  const float* gamma = (const float*)d_in[9];
  const float* beta  = (const float*)d_in[10];

  char* ws = (char*)d_ws;
  u16*   theta = (u16*)(ws + 0);
  u16*   kproj = (u16*)(ws + 4194304);
  u16*   gT    = (u16*)(ws + 8388608);
  u16*   pO    = (u16*)(ws + 12582912);
  float* pM    = (float*)(ws + 29360128);
  float* pL    = (float*)(ws + 29622272);
  u16*   wy    = (u16*)(ws + 29884416);
  float* stats = (float*)(ws + 38273024);
  float* out   = (float*)d_out;

  k1_proj<<<256, 512, 0, stream>>>(x, Wt, Wp, Wg, bt, bp, bg, theta, kproj, gT, stats);
  k2_attn<<<256, 512, 0, stream>>>(theta, kproj, gT, pO, pM, pL);
  k3_wy<<<256, 512, 0, stream>>>(pO, pM, pL, Ww, bw, wy, stats);
  k4_bn<<<2048, 256, 0, stream>>>(wy, x, stats, gamma, beta, out);
}

// Round 19
// 120.635 us; speedup vs baseline: 1.0028x; 1.0028x over previous
//
#include <hip/hip_runtime.h>
#include <cstdint>
#include <cstddef>

// NonLocalBlock3D: B=2, C=256, Ci=128, N=D*H*W=8192.
// k1 projections (512thr, half-split + W-prefetch dbuf) -> k2 flash attention (CH=4,
// 2-tiles/barrier, 256B-row K+V swizzle) -> k3 combine+wy GEMM+stats (512thr, W-prefetch)
// -> k4 BN+res.   == exact R14 configuration (best measured passing: 120.74us) ==
// R3: never cap k2 VGPR via launch_bounds min-waves (spills). (512,2) safe.
// R4: k2 unified regs ~168/wave -> 2 waves/SIMD hard cap.
// R6: global_load_lds staging regressed. Keep reg-staged write-late.
// R7/R8: __builtin_amdgcn_exp2f; (row&15)<<4 swizzle over 256B rows.
// R9/R10/R11/R13/R15: k2 micro-structure all NEUTRAL (deferred-SM, barrier-halving,
//   reg-blocking, V-conflict fix, parity-stagger). R12/R14 tail prefetch: WIN.
// R16-R18: permlane32_swap-based softmax reduce failed correctness 3x (semantics not
//   validated in reduce context) -> ABANDONED; __shfl_xor(x,32) retained.

typedef unsigned short u16;
typedef __bf16 bf16x8 __attribute__((ext_vector_type(8)));
typedef float f32x4 __attribute__((ext_vector_type(4)));
typedef float f32x16 __attribute__((ext_vector_type(16)));
typedef unsigned short u16x8 __attribute__((ext_vector_type(8)));

#define B_ 2
#define C_ 256
#define CI_ 128
#define N_ 8192
#define KVB 64

static __device__ __forceinline__ u16 f2bf(float f){
  unsigned u = __builtin_bit_cast(unsigned, f);
  unsigned r = (u + 0x7FFFu + ((u>>16)&1u)) >> 16;
  return (u16)r;
}
static __device__ __forceinline__ float bf2f(u16 v){
  unsigned u = ((unsigned)v) << 16;
  return __builtin_bit_cast(float, u);
}
static __device__ __forceinline__ float fexp2(float x){
  return __builtin_amdgcn_exp2f(x);     // raw v_exp_f32
}
static __device__ __forceinline__ f32x4 f4zero(){
  f32x4 v; v[0]=0.f; v[1]=0.f; v[2]=0.f; v[3]=0.f; return v;
}
static __device__ __forceinline__ f32x16 f16zero(){
  f32x16 v;
#pragma unroll
  for (int i=0;i<16;i++) v[i]=0.f;
  return v;
}
static __device__ __forceinline__ f32x4 mfma16(bf16x8 a, bf16x8 b, f32x4 c){
  return __builtin_amdgcn_mfma_f32_16x16x32_bf16(a, b, c, 0, 0, 0);
}
static __device__ __forceinline__ f32x16 mfma32(bf16x8 a, bf16x8 b, f32x16 c){
  return __builtin_amdgcn_mfma_f32_32x32x16_bf16(a, b, c, 0, 0, 0);
}
static __device__ __forceinline__ unsigned cvtpk(float lo, float hi){
  unsigned r;
  asm("v_cvt_pk_bf16_f32 %0, %1, %2" : "=v"(r) : "v"(lo), "v"(hi));
  return r;
}
static __device__ __forceinline__ void plswap(unsigned &a, unsigned &b){
  asm volatile("v_permlane32_swap_b32 %0, %1" : "+v"(a), "+v"(b));
}

#define LOG2E 1.4426950408889634f

// ---------------- K1: fused weight pack + transpose + 3 projections ----------------
// 512 threads, 8 waves. Wave-halves split the 12 chunks (6 each); per-half W LDS is
// double-buffered with register prefetch of chunk i+1 (write-late).
__global__ __launch_bounds__(512) void k1_proj(const float* __restrict__ x,
     const float* __restrict__ Wt, const float* __restrict__ Wp,
     const float* __restrict__ Wg, const float* __restrict__ bt,
     const float* __restrict__ bp, const float* __restrict__ bg,
     u16* __restrict__ theta, u16* __restrict__ kproj, u16* __restrict__ gT,
     float* __restrict__ stats){
  __shared__ u16 At[64*264];            // 33792 B
  __shared__ u16 Wt2[2][2][32*264];     // [half][buf], 4 x 16896 B
  int tid = threadIdx.x;
  int b  = blockIdx.x >> 7;
  int nb = (blockIdx.x & 127) * 64;
  int w = tid >> 6, lane = tid & 63;
  int l15 = lane & 15, kg = lane >> 4;
  int half = w >> 2, wq = w & 3;
  int ht = tid & 255;
  int o8 = ht>>3, cp8 = ht&7;

  if (blockIdx.x == 0){ stats[tid] = 0.f; }

  auto wrow = [&](int och)->const float* {
    return (och<4) ? (Wt + ((size_t)(och*32 + o8))*256)
         : (och<8) ? (Wp + ((size_t)((och-4)*32 + o8))*256)
                   : (Wg + ((size_t)((och-8)*32 + o8))*256);
  };

  // stage A tile [64 n][256 c] bf16 (transposed from x)
  {
    int cp = tid & 127, nh = tid >> 7;
    int c0 = cp*2;
    const float* src0 = x + ((size_t)(b*C_ + c0))*N_ + nb + nh*16;
    const float* src1 = src0 + N_;
#pragma unroll
    for (int j=0;j<4;j++){
      f32x4 a = *(const f32x4*)(src0 + j*4);
      f32x4 c = *(const f32x4*)(src1 + j*4);
#pragma unroll
      for (int q=0;q<4;q++){
        unsigned pk = (unsigned)f2bf(a[q]) | ((unsigned)f2bf(c[q])<<16);
        *(unsigned*)&At[(nh*16 + j*4 + q)*264 + c0] = pk;
      }
    }
  }
  // stage W chunk (half*6) into buf 0
  {
    int och = half*6;
    const float* src = wrow(och) + cp8*8;
    float scl = (och<4) ? LOG2E : 1.f;
#pragma unroll
    for (int j=0;j<4;j++){
      f32x4 w0 = *(const f32x4*)(src + j*64);
      f32x4 w1 = *(const f32x4*)(src + j*64 + 4);
      u16 tmp[8];
#pragma unroll
      for (int q=0;q<4;q++){ tmp[q] = f2bf(w0[q]*scl); tmp[4+q] = f2bf(w1[q]*scl); }
      *(u16x8*)&Wt2[half][0][o8*264 + cp8*8 + j*64] = *(const u16x8*)tmp;
    }
  }
  __syncthreads();

  bf16x8 afr[8];
#pragma unroll
  for (int kc=0;kc<8;kc++)
    afr[kc] = *(const bf16x8*)&At[(wq*16+l15)*264 + kc*32 + kg*8];

  for (int i = 0; i < 6; i++){
    int och = half*6 + i;
    // prefetch next W chunk into registers (write-late)
    f32x4 pw[8];
    if (i < 5){
      const float* src = wrow(och+1) + cp8*8;
#pragma unroll
      for (int j=0;j<4;j++){
        pw[2*j]   = *(const f32x4*)(src + j*64);
        pw[2*j+1] = *(const f32x4*)(src + j*64 + 4);
      }
    }

    f32x4 acc0 = f4zero(), acc1 = f4zero();
    const u16* wb = &Wt2[half][i&1][0];
#pragma unroll
    for (int kc=0;kc<8;kc++){
      bf16x8 b0 = *(const bf16x8*)&wb[(l15)*264 + kc*32 + kg*8];
      bf16x8 b1 = *(const bf16x8*)&wb[(16+l15)*264 + kc*32 + kg*8];
      acc0 = mfma16(afr[kc], b0, acc0);
      acc1 = mfma16(afr[kc], b1, acc1);
    }

    // write-late: staged W regs -> other buffer
    if (i < 5){
      float scl = (och+1<4) ? LOG2E : 1.f;
#pragma unroll
      for (int j=0;j<4;j++){
        u16 tmp[8];
#pragma unroll
        for (int q=0;q<4;q++){ tmp[q] = f2bf(pw[2*j][q]*scl); tmp[4+q] = f2bf(pw[2*j+1][q]*scl); }
        *(u16x8*)&Wt2[half][(i+1)&1][o8*264 + cp8*8 + j*64] = *(const u16x8*)tmp;
      }
    }

    if (och < 8){
      u16* dst = (och < 4) ? theta : kproj;
      int oo = (och & 3) * 32;
#pragma unroll
      for (int of=0;of<2;of++){
        int o = oo + of*16 + l15;
        float bias = (och<4) ? bt[och*32 + of*16 + l15] * LOG2E
                             : bp[(och-4)*32 + of*16 + l15];
        f32x4 acc = of ? acc1 : acc0;
#pragma unroll
        for (int i2=0;i2<4;i2++){
          int n = nb + wq*16 + kg*4 + i2;
          dst[((size_t)b*N_ + n)*CI_ + o] = f2bf(acc[i2] + bias);
        }
      }
    } else {
#pragma unroll
      for (int of=0;of<2;of++){
        int o = of*16 + l15;
        int og = (och-8)*32 + o;
        float bias = bg[og];
        f32x4 acc = of ? acc1 : acc0;
        unsigned lo = (unsigned)f2bf(acc[0]+bias) | ((unsigned)f2bf(acc[1]+bias)<<16);
        unsigned hi2 = (unsigned)f2bf(acc[2]+bias) | ((unsigned)f2bf(acc[3]+bias)<<16);
        uint2 val; val.x = lo; val.y = hi2;
        *(uint2*)(gT + ((size_t)b*CI_ + og)*N_ + nb + wq*16 + kg*4) = val;
      }
    }
    __syncthreads();
  }
}

// ---------------- K2: flash attention, 2 tiles/barrier, merged 256B-row V ----------------
// Grid 256 x 512 (8 waves x 32 q). bid&7 = (b,chunk) -> XCD.
// LDS 128K: K halves [2][2 tiles][16K] at 0; V halves [2][128 c][256B] at 64K.
// Both K and V rows 256B with (row&15)<<4 XOR swizzle; tile-B V offset = kro^128.
__global__ __launch_bounds__(512, 2) void k2_attn(const u16* __restrict__ theta,
      const u16* __restrict__ kproj, const u16* __restrict__ gT,
      u16* __restrict__ pO, float* __restrict__ pM, float* __restrict__ pL){
  constexpr int CHUNK_N = 2048;
  constexpr int NTI = CHUNK_N / KVB;   // 32
  constexpr int NS  = NTI/2;           // 16 super-iters
  __shared__ char smem[131072];
  char* kbase = smem;
  char* vbase = smem + 65536;
  int tid = threadIdx.x;
  int bid = blockIdx.x;
  int combo = bid & 7;
  int b = combo & 1;
  int chunk = combo >> 1;
  int qblk = bid >> 3;
  int n0 = chunk * CHUNK_N;
  int w = tid >> 6, lane = tid & 63;
  int l31 = lane & 31, hi = lane >> 5;
  int qg = qblk*256 + w*32 + l31;

  bf16x8 qf[8];
  {
    const u16* qsrc = theta + ((size_t)b*N_ + qg)*CI_ + hi*8;
#pragma unroll
    for (int cc=0; cc<8; cc++) qf[cc] = *(const bf16x8*)(qsrc + cc*16);
  }

  int krow_s = tid >> 3, kpart = tid & 7;
  int vrow_s = tid >> 2, vpart = tid & 3;
  const u16* ksrc = kproj + ((size_t)b*N_ + n0 + krow_s)*CI_ + kpart*16;
  const u16* vsrc = gT + ((size_t)b*CI_ + vrow_s)*N_ + n0 + vpart*32;
  int kw_off[2], vw_off[4];
#pragma unroll
  for (int j=0;j<2;j++){
    int cb = kpart*32 + j*16;
    kw_off[j] = krow_s*256 + (cb ^ ((krow_s&15)<<4));
  }
#pragma unroll
  for (int j=0;j<4;j++){
    vw_off[j] = vrow_s*256 + ((vpart*64 + j*16) ^ ((vrow_s&15)<<4));
  }
  int kswz = (l31&15)<<4;
  int kro[8];
#pragma unroll
  for (int cc=0;cc<8;cc++) kro[cc] = l31*256 + ((cc*32 + hi*16) ^ kswz);

  // prologue: stage pair 0 into half 0
#pragma unroll
  for (int j=0;j<2;j++){
    *(u16x8*)(kbase + kw_off[j])         = *(const u16x8*)(ksrc + j*8);
    *(u16x8*)(kbase + 16384 + kw_off[j]) = *(const u16x8*)(ksrc + (size_t)KVB*CI_ + j*8);
  }
#pragma unroll
  for (int j=0;j<4;j++)
    *(u16x8*)(vbase + vw_off[j]) = *(const u16x8*)(vsrc + j*8);
  __syncthreads();

  f32x16 oacc[4];
#pragma unroll
  for (int i=0;i<4;i++) oacc[i] = f16zero();
  float mrun = -1e30f, lrun = 0.f;

#define K2_TILE(KB, VB, VX) { \
    f32x16 sA = f16zero(), sB = f16zero(); \
    __builtin_amdgcn_s_setprio(1); \
    _Pragma("unroll") \
    for (int cc=0; cc<8; cc++){ \
      bf16x8 kf0 = *(const bf16x8*)((KB) + kro[cc]); \
      bf16x8 kf1 = *(const bf16x8*)((KB) + 8192 + kro[cc]); \
      sA = mfma32(kf0, qf[cc], sA); \
      sB = mfma32(kf1, qf[cc], sB); \
    } \
    __builtin_amdgcn_s_setprio(0); \
    float t8[8]; \
    _Pragma("unroll") \
    for (int i=0;i<8;i++) t8[i] = fmaxf(fmaxf(sA[i], sA[i+8]), fmaxf(sB[i], sB[i+8])); \
    float mx = fmaxf(fmaxf(fmaxf(t8[0],t8[4]),fmaxf(t8[1],t8[5])), \
                     fmaxf(fmaxf(t8[2],t8[6]),fmaxf(t8[3],t8[7]))); \
    mx = fmaxf(mx, __shfl_xor(mx, 32)); \
    if (__any(mx > mrun + 12.f)){ \
      float mnew = fmaxf(mrun, mx); \
      float sc = fexp2(mrun - mnew); \
      lrun *= sc; \
      _Pragma("unroll") \
      for (int i=0;i<4;i++){ _Pragma("unroll") for (int r=0;r<16;r++) oacc[i][r] *= sc; } \
      mrun = mnew; } \
    float pA[16], pB[16]; \
    _Pragma("unroll") \
    for (int r=0;r<16;r++){ pA[r] = fexp2(sA[r]-mrun); pB[r] = fexp2(sB[r]-mrun); } \
    { float s8[8]; \
      _Pragma("unroll") \
      for (int i=0;i<8;i++) s8[i] = (pA[i]+pA[i+8]) + (pB[i]+pB[i+8]); \
      float ps = ((s8[0]+s8[4])+(s8[1]+s8[5])) + ((s8[2]+s8[6])+(s8[3]+s8[7])); \
      ps += __shfl_xor(ps, 32); lrun += ps; } \
    __builtin_amdgcn_s_setprio(1); \
    _Pragma("unroll") \
    for (int ks=0; ks<4; ks++){ \
      const float* P = (ks<2) ? pA : pB; \
      int r0 = (ks&1)*8; \
      unsigned a0 = cvtpk(P[r0+0], P[r0+1]); \
      unsigned b0 = cvtpk(P[r0+4], P[r0+5]); \
      unsigned a1 = cvtpk(P[r0+2], P[r0+3]); \
      unsigned b1 = cvtpk(P[r0+6], P[r0+7]); \
      plswap(a0, b0); plswap(a1, b1); \
      union { unsigned u[4]; bf16x8 v; } pb; \
      pb.u[0]=a0; pb.u[1]=a1; pb.u[2]=b0; pb.u[3]=b1; \
      _Pragma("unroll") \
      for (int c2=0; c2<4; c2++){ \
        bf16x8 vf = *(const bf16x8*)((VB) + c2*8192 + (kro[ks] ^ (VX))); \
        oacc[c2] = mfma32(vf, pb.v, oacc[c2]); \
      } \
    } \
    __builtin_amdgcn_s_setprio(0); }

  for (int s = 0; s < NS; s++){
    int H = s & 1;
    char* kh = kbase + H*32768;
    char* vh = vbase + H*32768;
    u16x8 kst[4], vst[4];
    bool pf = (s+1 < NS);
    if (pf){
      const u16* ks = ksrc + (size_t)(2*s+2)*KVB*CI_;
      const u16* vs = vsrc + (size_t)(s+1)*128;
      kst[0] = *(const u16x8*)(ks);
      kst[1] = *(const u16x8*)(ks + 8);
      kst[2] = *(const u16x8*)(ks + (size_t)KVB*CI_);
      kst[3] = *(const u16x8*)(ks + (size_t)KVB*CI_ + 8);
#pragma unroll
      for (int j=0;j<4;j++) vst[j] = *(const u16x8*)(vs + j*8);
    }

    // tile A = 2s
    K2_TILE(kh, vh, 0)

    // write-late: staged regs -> other half (hides load latency under tile A)
    if (pf){
      char* kd = kbase + (H^1)*32768;
      char* vd = vbase + (H^1)*32768;
#pragma unroll
      for (int j=0;j<2;j++){
        *(u16x8*)(kd + kw_off[j])         = kst[j];
        *(u16x8*)(kd + 16384 + kw_off[j]) = kst[2+j];
      }
#pragma unroll
      for (int j=0;j<4;j++)
        *(u16x8*)(vd + vw_off[j]) = vst[j];
    }

    // tile B = 2s+1
    K2_TILE(kh + 16384, vh, 128)

    __syncthreads();
  }

  // epilogue: O^T -> per-wave LDS region (bf16, swizzled) -> coalesced partial store
  char* region = smem + w*8192;
  int eswz = (l31&7)<<4;
#pragma unroll
  for (int c2=0;c2<4;c2++)
#pragma unroll
    for (int r=0;r<16;r++){
      int c = c2*32 + (r&3) + 8*(r>>2) + 4*hi;
      *(u16*)(region + l31*256 + ((c*2) ^ eswz)) = f2bf(oacc[c2][r]);
    }
  __syncthreads();
  {
    int ql = lane >> 1, half = lane & 1;
    int qg2 = qblk*256 + w*32 + ql;
    u16* dst = pO + ((size_t)(chunk*2 + b)*N_ + qg2)*CI_ + half*64;
    int rswz = (ql&7)<<4;
#pragma unroll
    for (int j=0;j<8;j++){
      u16x8 v2 = *(const u16x8*)(region + ql*256 + ((half*128 + j*16) ^ rswz));
      *(u16x8*)(dst + j*8) = v2;
    }
  }
  if (hi == 0){
    pM[(size_t)(chunk*2 + b)*N_ + qg] = mrun;
    pL[(size_t)(chunk*2 + b)*N_ + qg] = lrun;
  }
}

// ---------------- K3: fused combine(pO chunks) + wy = Ww @ y + bw + stats ----------------
// 512 threads, 8 waves. Wave-halves split the 4 oc chunks (2 each); W dbuf + prefetch.
__global__ __launch_bounds__(512) void k3_wy(const u16* __restrict__ pO,
    const float* __restrict__ pM, const float* __restrict__ pL,
    const float* __restrict__ Ww, const float* __restrict__ bw,
    u16* __restrict__ wy, float* __restrict__ stats){
  __shared__ u16 Yt[64*136];            // 17408
  __shared__ u16 Wt2[2][2][64*136];     // 4 x 17408
  __shared__ float wyb2[2][64*72];      // 2 x 18432
  int tid = threadIdx.x;
  int b  = blockIdx.x >> 7;
  int nb = (blockIdx.x & 127) * 64;
  int w = tid>>6, lane = tid&63;
  int l15 = lane&15, kg = lane>>4;
  int half = w >> 2, wq = w & 3;
  int ht = tid & 255;
  int o4 = ht>>2, cp4 = ht&3;

  // stage y tile [64 n][128 c]: combine 4 KV-chunk partials -> bf16
  {
    int n = tid>>3, cp = tid&7;
    size_t q = (size_t)nb + n;
    float m[4], l[4];
#pragma unroll
    for (int ch=0; ch<4; ch++){
      m[ch] = pM[(size_t)(ch*2+b)*N_ + q];
      l[ch] = pL[(size_t)(ch*2+b)*N_ + q];
    }
    float M = fmaxf(fmaxf(m[0],m[1]), fmaxf(m[2],m[3]));
    float wts[4]; float L = 0.f;
#pragma unroll
    for (int ch=0; ch<4; ch++){ wts[ch] = fexp2(m[ch]-M); L += wts[ch]*l[ch]; }
    float inv = 1.f/L;
#pragma unroll
    for (int j=0;j<2;j++){
      int c0 = cp*16 + j*8;
      float acc[8];
#pragma unroll
      for (int i=0;i<8;i++) acc[i]=0.f;
#pragma unroll
      for (int ch=0; ch<4; ch++){
        u16x8 v = *(const u16x8*)(pO + ((size_t)(ch*2+b)*N_ + q)*CI_ + c0);
#pragma unroll
        for (int i=0;i<8;i++) acc[i] += wts[ch]*bf2f(v[i]);
      }
#pragma unroll
      for (int i=0;i<4;i++){
        unsigned pk = (unsigned)f2bf(acc[2*i]*inv) | ((unsigned)f2bf(acc[2*i+1]*inv)<<16);
        *(unsigned*)&Yt[n*136 + c0 + 2*i] = pk;
      }
    }
  }
  // stage W chunk (half*2) into buf 0
  {
    const float* src = Ww + ((size_t)(half*2*64 + o4))*CI_ + cp4*32;
#pragma unroll
    for (int j=0;j<4;j++){
      f32x4 w0 = *(const f32x4*)(src + j*8);
      f32x4 w1 = *(const f32x4*)(src + j*8 + 4);
      u16 tmp[8];
#pragma unroll
      for (int q2=0;q2<4;q2++){ tmp[q2] = f2bf(w0[q2]); tmp[4+q2] = f2bf(w1[q2]); }
      *(u16x8*)&Wt2[half][0][o4*136 + cp4*32 + j*8] = *(const u16x8*)tmp;
    }
  }
  __syncthreads();

  bf16x8 afr[4];
#pragma unroll
  for (int kc=0;kc<4;kc++)
    afr[kc] = *(const bf16x8*)&Yt[(wq*16+l15)*136 + kc*32 + kg*8];

  for (int i = 0; i < 2; i++){
    int oc = half*2 + i;
    // prefetch next W chunk into regs
    f32x4 pw[8];
    if (i == 0){
      const float* src = Ww + ((size_t)((oc+1)*64 + o4))*CI_ + cp4*32;
#pragma unroll
      for (int j=0;j<4;j++){
        pw[2*j]   = *(const f32x4*)(src + j*8);
        pw[2*j+1] = *(const f32x4*)(src + j*8 + 4);
      }
    }

    f32x4 acc[4];
#pragma unroll
    for (int of=0;of<4;of++) acc[of] = f4zero();
    const u16* wb = &Wt2[half][i][0];
#pragma unroll
    for (int kc=0;kc<4;kc++){
#pragma unroll
      for (int of=0;of<4;of++){
        bf16x8 bfr = *(const bf16x8*)&wb[(of*16+l15)*136 + kc*32 + kg*8];
        acc[of] = mfma16(afr[kc], bfr, acc[of]);
      }
    }
#pragma unroll
    for (int of=0;of<4;of++){
#pragma unroll
      for (int i2=0;i2<4;i2++)
        wyb2[half][(of*16+l15)*72 + wq*16 + kg*4 + i2] = acc[of][i2];
    }
    // write-late: staged W regs -> buf 1
    if (i == 0){
#pragma unroll
      for (int j=0;j<4;j++){
        u16 tmp[8];
#pragma unroll
        for (int q2=0;q2<4;q2++){ tmp[q2] = f2bf(pw[2*j][q2]); tmp[4+q2] = f2bf(pw[2*j+1][q2]); }
        *(u16x8*)&Wt2[half][1][o4*136 + cp4*32 + j*8] = *(const u16x8*)tmp;
      }
    }
    __syncthreads();
    {
      int og = oc*64 + o4;
      float bias = bw[og];
      float sm = 0.f, sq = 0.f;
      u16* dst = wy + ((size_t)b*C_ + og)*N_ + nb + cp4*16;
      u16 buf[16];
#pragma unroll
      for (int j=0;j<4;j++){
#pragma unroll
        for (int q2=0;q2<4;q2++){
          float t2 = wyb2[half][o4*72 + cp4*16 + j*4 + q2] + bias;
          buf[j*4+q2] = f2bf(t2); sm += t2; sq += t2*t2;
        }
      }
      *(u16x8*)dst = *(const u16x8*)&buf[0];
      *(u16x8*)(dst+8) = *(const u16x8*)&buf[8];
      sm += __shfl_xor(sm, 1); sm += __shfl_xor(sm, 2);
      sq += __shfl_xor(sq, 1); sq += __shfl_xor(sq, 2);
      if ((tid&3)==0){
        atomicAdd(&stats[og], sm);
        atomicAdd(&stats[256+og], sq);
      }
    }
    __syncthreads();
  }
}

// ---------------- K4: BN (batch stats) + residual ----------------
__global__ __launch_bounds__(256) void k4_bn(const u16* __restrict__ wy,
    const float* __restrict__ x, const float* __restrict__ stats,
    const float* __restrict__ gamma, const float* __restrict__ beta,
    float* __restrict__ out){
  size_t base = ((size_t)blockIdx.x)*2048 + (size_t)threadIdx.x*8;
  int o = (int)((base >> 13) & 255);
  const float invn = 1.f/16384.f;
  float mean = stats[o]*invn;
  float var  = stats[256+o]*invn - mean*mean;
  float rs = rsqrtf(var + 1e-5f);
  float g = gamma[o]*rs;
  float bb = beta[o];
  u16x8 a = *(const u16x8*)(wy + base);
  f32x4 x0 = *(const f32x4*)(x + base);
  f32x4 x1 = *(const f32x4*)(x + base + 4);
  f32x4 r0, r1;
#pragma unroll
  for (int q=0;q<4;q++){
    r0[q] = (bf2f(a[q])-mean)*g + bb + x0[q];
    r1[q] = (bf2f(a[4+q])-mean)*g + bb + x1[q];
  }
  *(f32x4*)(out + base)     = r0;
  *(f32x4*)(out + base + 4) = r1;
}

extern "C" void kernel_launch(void* const* d_in, const int* in_sizes, int n_in,
                              void* d_out, int out_size, void* d_ws, size_t ws_size,
                              hipStream_t stream){
  const float* x     = (const float*)d_in[0];
  const float* Wt    = (const float*)d_in[1];
  const float* bt    = (const float*)d_in[2];
  const float* Wp    = (const float*)d_in[3];
  const float* bp    = (const float*)d_in[4];
  const float* Wg    = (const float*)d_in[5];
  const float* bg    = (const float*)d_in[6];
  const float* Ww    = (const float*)d_in[7];
  const float* bw    = (const float*)d_in[8];
  const float* gamma = (const float*)d_in[9];
  const float* beta  = (const float*)d_in[10];

  char* ws = (char*)d_ws;
  u16*   theta = (u16*)(ws + 0);
  u16*   kproj = (u16*)(ws + 4194304);
  u16*   gT    = (u16*)(ws + 8388608);
  u16*   pO    = (u16*)(ws + 12582912);
  float* pM    = (float*)(ws + 29360128);
  float* pL    = (float*)(ws + 29622272);
  u16*   wy    = (u16*)(ws + 29884416);
  float* stats = (float*)(ws + 38273024);
  float* out   = (float*)d_out;

  k1_proj<<<256, 512, 0, stream>>>(x, Wt, Wp, Wg, bt, bp, bg, theta, kproj, gT, stats);
  k2_attn<<<256, 512, 0, stream>>>(theta, kproj, gT, pO, pM, pL);
  k3_wy<<<256, 512, 0, stream>>>(pO, pM, pL, Ww, bw, wy, stats);
  k4_bn<<<2048, 256, 0, stream>>>(wy, x, stats, gamma, beta, out);
}